// Round 1
// baseline (634.819 us; speedup 1.0000x reference)
//
#include <hip/hip_runtime.h>
#include <math.h>

#define B 2
#define C 3
#define H 256
#define W 256
#define HW (H*W)            // 65536
#define NX (B*C*HW)         // 393216
#define NU (B*C*2*HW)       // 786432
#define K1_BLOCKS (NU/256)  // 3072
#define K2_BLOCKS (NX/256)  // 1536
#define K_STEPS 50

// init: x = y, xt = 0, u = nabla(y)
__global__ void cp_init(const float* __restrict__ y, float* __restrict__ x,
                        float* __restrict__ xt, float* __restrict__ u) {
    int j = blockIdx.x * 256 + threadIdx.x;      // x-domain index (b,c,h,w)
    int w  = j & (W - 1);
    int h  = (j >> 8) & (H - 1);
    int bc = j >> 16;                            // b*C + c
    float yv = y[j];
    x[j]  = yv;
    xt[j] = 0.0f;
    float dh = (h < H - 1) ? (y[j + W] - yv) : 0.0f;
    float dw = (w < W - 1) ? (y[j + 1] - yv) : 0.0f;
    int i0 = (bc * 2) * HW + (j & (HW - 1));     // u index (b,c,0,h,w)
    u[i0]      = dh;
    u[i0 + HW] = dw;
}

// K1: v = u + sigma * nabla(xt); per-block partial sum of v^2
__global__ void cp_k1(const float* __restrict__ u, const float* __restrict__ xt,
                      float* __restrict__ v, float* __restrict__ partials,
                      float sigma) {
    int i = blockIdx.x * 256 + threadIdx.x;      // u-domain index (b,c,d,h,w)
    int w   = i & (W - 1);
    int h   = (i >> 8) & (H - 1);
    int bcd = i >> 16;                           // b*C*2 + c*2 + d
    int d   = bcd & 1;
    int jx  = (bcd >> 1) * HW + (i & (HW - 1));  // matching x-domain index
    float g;
    if (d == 0) g = (h < H - 1) ? (xt[jx + W] - xt[jx]) : 0.0f;
    else        g = (w < W - 1) ? (xt[jx + 1] - xt[jx]) : 0.0f;
    float vv = u[i] + sigma * g;
    v[i] = vv;

    __shared__ float sdata[256];
    sdata[threadIdx.x] = vv * vv;
    __syncthreads();
    for (int s = 128; s > 0; s >>= 1) {
        if (threadIdx.x < s) sdata[threadIdx.x] += sdata[threadIdx.x + s];
        __syncthreads();
    }
    if (threadIdx.x == 0) partials[blockIdx.x] = sdata[0];
}

// K2: finish reduction -> scales; u' = v*scale; x' = (x - tau*nablaT(u') + tau*y)/(1+tau);
//     xt' = (1+chi)*x' - chi*x
__global__ void cp_k2(const float* __restrict__ v, const float* __restrict__ partials,
                      const float* __restrict__ y, const float* __restrict__ lambd,
                      float* __restrict__ x, float* __restrict__ xt, float* __restrict__ u,
                      float tau, float chi) {
    __shared__ float sred[256][4];
    __shared__ float s_scale[4];
    int tid = threadIdx.x;

    // Finish the (b,d) sum-of-squares reduction redundantly per block.
    // K1 block p covers u-flat range [p*256,(p+1)*256) which lies entirely in
    // one (b,c,d) slice (HW % 256 == 0). group g = b*2 + d.
    float acc0 = 0.f, acc1 = 0.f, acc2 = 0.f, acc3 = 0.f;
    for (int p = tid; p < K1_BLOCKS; p += 256) {
        int q = p >> 8;          // (p*256)>>16, in [0,12)  == b*6 + c*2 + d
        int b = q / 6;
        int d = q & 1;
        int g = b * 2 + d;
        float val = partials[p];
        if      (g == 0) acc0 += val;
        else if (g == 1) acc1 += val;
        else if (g == 2) acc2 += val;
        else             acc3 += val;
    }
    sred[tid][0] = acc0; sred[tid][1] = acc1; sred[tid][2] = acc2; sred[tid][3] = acc3;
    __syncthreads();
    for (int s = 128; s > 0; s >>= 1) {
        if (tid < s) {
            sred[tid][0] += sred[tid + s][0];
            sred[tid][1] += sred[tid + s][1];
            sred[tid][2] += sred[tid + s][2];
            sred[tid][3] += sred[tid + s][3];
        }
        __syncthreads();
    }
    if (tid < 4) {
        float lamb = expf(lambd[0]);
        float nrm  = sqrtf(sred[0][tid]);
        s_scale[tid] = lamb / fmaxf(nrm, lamb);
    }
    __syncthreads();

    int j  = blockIdx.x * 256 + tid;             // x-domain index
    int w  = j & (W - 1);
    int h  = (j >> 8) & (H - 1);
    int bc = j >> 16;
    int b  = bc / C;
    float s0 = s_scale[b * 2];
    float s1 = s_scale[b * 2 + 1];
    int i0 = (bc * 2) * HW + (j & (HW - 1));
    int i1 = i0 + HW;

    float u0c = v[i0] * s0;
    float u1c = v[i1] * s1;
    u[i0] = u0c;
    u[i1] = u1c;

    float nt = 0.0f;
    if (h >= 1)     nt += v[i0 - W] * s0;
    if (h <= H - 2) nt -= u0c;
    if (w >= 1)     nt += v[i1 - 1] * s1;
    if (w <= W - 2) nt -= u1c;

    float xold = x[j];
    float xnew = (xold - tau * nt + tau * y[j]) / (1.0f + tau);
    x[j]  = xnew;
    xt[j] = (1.0f + chi) * xnew - chi * xold;
}

extern "C" void kernel_launch(void* const* d_in, const int* in_sizes, int n_in,
                              void* d_out, int out_size, void* d_ws, size_t ws_size,
                              hipStream_t stream) {
    const float* y     = (const float*)d_in[0];
    const float* lambd = (const float*)d_in[1];
    float* x  = (float*)d_out;          // [0 , NX)
    float* xt = x + NX;                 // [NX, 2NX)
    float* u  = x + 2 * NX;             // [2NX, 2NX+NU)
    float* v        = (float*)d_ws;     // NU floats
    float* partials = v + NU;           // K1_BLOCKS floats

    cp_init<<<K2_BLOCKS, 256, 0, stream>>>(y, x, xt, u);

    float sigma = (float)(0.5 / sqrt(6.0));   // 0.5/sqrt(2*C)
    float tau   = sigma;
    for (int t = 0; t < K_STEPS; ++t) {
        cp_k1<<<K1_BLOCKS, 256, 0, stream>>>(u, xt, v, partials, sigma);
        float chi = 1.0f / sqrtf(1.0f + tau);   // 1/sqrt(1 + 2*RHO*tau), RHO=0.5
        cp_k2<<<K2_BLOCKS, 256, 0, stream>>>(v, partials, y, lambd, x, xt, u, tau, chi);
        tau   *= chi;
        sigma /= chi;
    }
}